// Round 3
// baseline (320.017 us; speedup 1.0000x reference)
//
#include <hip/hip_runtime.h>

#define K_CODES 512
#define DIM 64
#define HW 1024
#define NVEC 65536
#define NREP 4

// Output offsets (flat concat, reference return order)
#define O0 0             // loss (1)
#define O1 1             // out_q NCHW (4194304)
#define O2 4194305       // perplexity (1)
#define O3 4194306       // idx as float (65536)
#define O4 4259842       // new_cs (512)
#define O5 4260354       // new_ema_w (32768)
#define O6 4293122       // new_embedding (32768)

// ws float layout:
// [0..512)          = ee (||e_k||^2)
// [512..2560)       = counts, 4 replicas x 512 (int)
// [2560..4608)      = per-block loss partials (2048)
// [4608]            = n (0.99*sum(ema_cs) + 0.01*65536)
// [4864..4199168)   = flat x rows (65536 x 64 fp32, NHWC-flattened)
// [4199168..)       = B-pack (98304 bf16, MFMA-frag order)
#define WS_EE   0
#define WS_CNT  512
#define WS_LOSS 2560
#define WS_N    4608
#define WS_FLAT 4864
#define WS_BP   4199168

#define LISTCAP 12288

typedef __bf16 bf16x8 __attribute__((ext_vector_type(8)));
typedef float  f32x4  __attribute__((ext_vector_type(4)));

__global__ void k0_init(const float* __restrict__ emb, const float* __restrict__ ema_cs,
                        float* __restrict__ wsf) {
    __shared__ float sn[256];
    const int b = blockIdx.x, t = threadIdx.x;
    if (b == 0) {
        int* cnt = (int*)(wsf + WS_CNT);
        #pragma unroll
        for (int i = 0; i < 8; ++i) cnt[i * 256 + t] = 0;   // zero 4 cnt replicas
        sn[t] = ema_cs[t] + ema_cs[t + 256];
        __syncthreads();
        for (int s = 128; s > 0; s >>= 1) {
            if (t < s) sn[t] += sn[t + s];
            __syncthreads();
        }
        if (t == 0) wsf[WS_N] = 0.99f * sn[0] + 0.01f * 65536.0f;  // n (counts sum to NVEC)
    } else if (b < 3) {
        int k = (b - 1) * 256 + t;                       // 0..511
        const float* e = emb + k * DIM;
        float s = 0.0f;
        #pragma unroll
        for (int c = 0; c < DIM; ++c) s += e[c] * e[c];
        wsf[WS_EE + k] = s;                              // ||e_k||^2
    } else {
        // Pack bf16 3-way split of (-2*e) into MFMA B-fragment order:
        // frag(s, ntg, ks): lane l holds B^T[code = ntg*16 + (l&15)][c = ks*32 + (l>>4)*8 + j]
        int g = (b - 3) * 256 + t;                       // 0..98303
        int j    = g & 7;
        int lane = (g >> 3) & 63;
        int ks   = (g >> 9) & 1;
        int rest = g >> 10;                              // 0..95
        int ntg  = rest & 31;
        int s    = rest >> 5;                            // split 0..2
        int code = ntg * 16 + (lane & 15);
        int c    = ks * 32 + (lane >> 4) * 8 + j;
        float v = -2.0f * emb[code * DIM + c];
        __bf16 h0 = (__bf16)v;  float r1 = v  - (float)h0;
        __bf16 h1 = (__bf16)r1; float r2 = r1 - (float)h1;
        __bf16 hv = (s == 0) ? h0 : (s == 1 ? h1 : (__bf16)r2);
        ((__bf16*)(wsf + WS_BP))[g] = hv;
    }
}

// Block: 256 threads = 4 waves; 32 vectors x 512 codes per block (2048 blocks).
// Wave ni: 32-vector x 128-code tile = 2x8 MFMA 16x16 tiles, acc[2][8]=64 AGPR.
// NO fp32 atomics: x rows plain-stored to flat ws buffer; k2 does the segment-sum.
__global__ __launch_bounds__(256, 4)
void k1_main(const float* __restrict__ in, const float* __restrict__ emb,
             float* __restrict__ out, float* __restrict__ wsf) {
    __shared__ float xs[32 * 65];            // fp32 x tile, row stride 65
    __shared__ unsigned int xsp[3][32 * 36]; // bf16 splits, packed pairs; row stride 36 uints
    __shared__ float pmin[4][32];
    __shared__ int   pidx[4][32];
    __shared__ float xxs[32];
    __shared__ int   hist[K_CODES];

    const int t    = threadIdx.x;
    const int lane = t & 63;
    const int wave = t >> 6;           // 0..3
    const int ni   = wave;             // 128-code quarter
    const int col  = lane & 15;
    const int quad = lane >> 4;

    hist[t] = 0; hist[t + 256] = 0;

    const int blk     = blockIdx.x;                    // 0..2047
    const int rep     = blk & (NREP - 1);              // cnt atomic replica
    const int n_img   = blk >> 5;
    const int hw_base = (blk & 31) * 32;
    const float* xbase = in + n_img * (DIM * HW) + hw_base;

    // Stage x: 32 vectors x 64 c, coalesced global reads
    #pragma unroll
    for (int it = 0; it < 8; ++it) {
        int e = it * 256 + t;
        int c = e >> 5, h = e & 31;
        xs[h * 65 + c] = xbase[c * HW + h];
    }

    // Accumulators init with ||e||^2 (d = ee - 2<x,e>)
    f32x4 acc[2][8];
    #pragma unroll
    for (int nt = 0; nt < 8; ++nt) {
        float eev = wsf[WS_EE + ni * 128 + nt * 16 + col];
        #pragma unroll
        for (int mi = 0; mi < 2; ++mi) {
            acc[mi][nt][0] = eev; acc[mi][nt][1] = eev;
            acc[mi][nt][2] = eev; acc[mi][nt][3] = eev;
        }
    }

    __syncthreads();

    // Build bf16 3-split of x once (pairs packed into uint), + ||x||^2
    #pragma unroll
    for (int i = 0; i < 4; ++i) {
        int e = i * 256 + t;                 // 0..1023 c-pairs
        int row = e >> 5, cp = e & 31;
        float v0 = xs[row * 65 + 2 * cp];
        float v1 = xs[row * 65 + 2 * cp + 1];
        __bf16 a0 = (__bf16)v0; float ra = v0 - (float)a0;
        __bf16 a1 = (__bf16)ra; ra -= (float)a1;
        __bf16 a2 = (__bf16)ra;
        __bf16 b0 = (__bf16)v1; float rb = v1 - (float)b0;
        __bf16 b1 = (__bf16)rb; rb -= (float)b1;
        __bf16 b2 = (__bf16)rb;
        union { __bf16 h[2]; unsigned int u; } u0, u1, u2;
        u0.h[0] = a0; u0.h[1] = b0;
        u1.h[0] = a1; u1.h[1] = b1;
        u2.h[0] = a2; u2.h[1] = b2;
        xsp[0][row * 36 + cp] = u0.u;
        xsp[1][row * 36 + cp] = u1.u;
        xsp[2][row * 36 + cp] = u2.u;
    }
    if (t < 32) {
        float s = 0.0f;
        #pragma unroll
        for (int c = 0; c < DIM; ++c) { float v = xs[t * 65 + c]; s += v * v; }
        xxs[t] = s;
    }

    // flat rows for k2's gather (plain coalesced stores, fire-and-forget)
    #pragma unroll
    for (int v8 = 0; v8 < 8; ++v8) {
        int v = wave * 8 + v8;
        wsf[WS_FLAT + (blk * 32 + v) * 64 + lane] = xs[v * 65 + lane];
    }
    __syncthreads();

    const bf16x8* bp8 = (const bf16x8*)(wsf + WS_BP);

    // K-loop: 2 k-steps x 6 split-pairs {(0,0),(1,0),(2,0),(0,1),(1,1),(0,2)}
    #pragma unroll
    for (int ks = 0; ks < 2; ++ks) {
        bf16x8 A0[2], A1[2], A2[2];
        #pragma unroll
        for (int mi = 0; mi < 2; ++mi) {
            int u = (mi * 16 + col) * 36 + ks * 16 + quad * 4;
            A0[mi] = *(const bf16x8*)&xsp[0][u];
            A1[mi] = *(const bf16x8*)&xsp[1][u];
            A2[mi] = *(const bf16x8*)&xsp[2][u];
        }
        #pragma unroll
        for (int s = 0; s < 3; ++s) {
            #pragma unroll
            for (int bh = 0; bh < 2; ++bh) {
                bf16x8 Bv[4];
                #pragma unroll
                for (int n4 = 0; n4 < 4; ++n4) {
                    int nt = bh * 4 + n4;
                    Bv[n4] = bp8[(((s * 32 + ni * 8 + nt) * 2 + ks) * 64) + lane];
                }
                #pragma unroll
                for (int mi = 0; mi < 2; ++mi)
                    #pragma unroll
                    for (int n4 = 0; n4 < 4; ++n4)
                        acc[mi][bh * 4 + n4] = __builtin_amdgcn_mfma_f32_16x16x32_bf16(A0[mi], Bv[n4], acc[mi][bh * 4 + n4], 0, 0, 0);
                if (s < 2) {
                    #pragma unroll
                    for (int mi = 0; mi < 2; ++mi)
                        #pragma unroll
                        for (int n4 = 0; n4 < 4; ++n4)
                            acc[mi][bh * 4 + n4] = __builtin_amdgcn_mfma_f32_16x16x32_bf16(A1[mi], Bv[n4], acc[mi][bh * 4 + n4], 0, 0, 0);
                }
                if (s == 0) {
                    #pragma unroll
                    for (int mi = 0; mi < 2; ++mi)
                        #pragma unroll
                        for (int n4 = 0; n4 < 4; ++n4)
                            acc[mi][bh * 4 + n4] = __builtin_amdgcn_mfma_f32_16x16x32_bf16(A2[mi], Bv[n4], acc[mi][bh * 4 + n4], 0, 0, 0);
                }
            }
        }
    }

    // Argmin. C layout: col(code) = lane&15, row(vector) = quad*4 + reg.
    #pragma unroll
    for (int mi = 0; mi < 2; ++mi) {
        #pragma unroll
        for (int r = 0; r < 4; ++r) {
            float v  = acc[mi][0][r];
            int   bi = ni * 128 + col;
            #pragma unroll
            for (int nt = 1; nt < 8; ++nt) {            // ascending codes, strict < = first-min
                float u  = acc[mi][nt][r];
                int   ui = ni * 128 + nt * 16 + col;
                if (u < v) { v = u; bi = ui; }
            }
            #pragma unroll
            for (int off = 1; off < 16; off <<= 1) {    // 16-lane butterfly, idx tie-break
                float ov = __shfl_xor(v, off);
                int   oi = __shfl_xor(bi, off);
                if (ov < v || (ov == v && oi < bi)) { v = ov; bi = oi; }
            }
            if (col == 0) {
                int row = mi * 16 + quad * 4 + r;
                pmin[ni][row] = v;
                pidx[ni][row] = bi;
            }
        }
    }
    __syncthreads();

    // Combine the 4 n-quarters (ascending code ranges), then idx/loss/hist
    if (t < 32) {
        float v = pmin[0][t]; int bi = pidx[0][t];
        #pragma unroll
        for (int q = 1; q < 4; ++q) {
            float u = pmin[q][t]; int ui = pidx[q][t];
            if (u < v) { v = u; bi = ui; }
        }
        pidx[0][t] = bi;                                 // publish final idx
        out[O3 + blk * 32 + t] = (float)bi;
        atomicAdd(&hist[bi], 1);
        float ld = v + xxs[t];                           // d_min = xx + (ee - 2<x,e>)
        #pragma unroll
        for (int off = 16; off > 0; off >>= 1) ld += __shfl_down(ld, off);
        if (t == 0) wsf[WS_LOSS + blk] = ld;             // per-block loss partial
    }
    __syncthreads();

    // out_q: thread t -> vector v = t&31, c-octant t>>5; coalesced per c-plane
    {
        int v = t & 31, cq = t >> 5;
        int kv = pidx[0][v];
        const float* ew = emb + kv * DIM;
        float* oq = out + O1 + n_img * (DIM * HW) + hw_base + v;
        #pragma unroll
        for (int c = cq * 8; c < cq * 8 + 8; ++c) oq[c * HW] = ew[c];
    }

    // counts: tiny int atomics only (for perplexity / EMA counts)
    int* cnt = (int*)(wsf + WS_CNT);
    if (hist[t])       atomicAdd(&cnt[rep * 512 + t], hist[t]);
    if (hist[t + 256]) atomicAdd(&cnt[rep * 512 + t + 256], hist[t + 256]);
}

// k2: blocks 0..511 = one code each (scan idx, gather flat rows, EMA outputs);
// block 512 = loss + perplexity.
__global__ void k2(const float* __restrict__ ema_cs, const float* __restrict__ ema_w,
                   float* __restrict__ out, const float* __restrict__ wsf) {
    __shared__ int   list[LISTCAP];
    __shared__ int   lcnt;
    __shared__ float rpart[4][64];
    __shared__ float s1[256], s2[256];

    const int t = threadIdx.x;
    const int lane = t & 63;
    const int w = t >> 6;
    const int blk = blockIdx.x;

    if (blk == 512) {
        // loss: sum 2048 per-block partials
        float ls = 0.0f;
        #pragma unroll
        for (int j = 0; j < 8; ++j) ls += wsf[WS_LOSS + j * 256 + t];
        s1[t] = ls;
        // perplexity from counts
        const int* cnt = (const int*)(wsf + WS_CNT);
        float ca = 0.0f, cb = 0.0f;
        #pragma unroll
        for (int r = 0; r < NREP; ++r) {
            ca += (float)cnt[r * 512 + t];
            cb += (float)cnt[r * 512 + 256 + t];
        }
        float pa = ca * (1.0f / 65536.0f);
        float pb = cb * (1.0f / 65536.0f);
        s2[t] = pa * logf(pa + 1e-10f) + pb * logf(pb + 1e-10f);
        __syncthreads();
        for (int s = 128; s > 0; s >>= 1) {
            if (t < s) { s1[t] += s1[t + s]; s2[t] += s2[t + s]; }
            __syncthreads();
        }
        if (t == 0) {
            out[O0] = 0.25f * s1[0] * (1.0f / 4194304.0f);
            out[O2] = expf(-s2[0]);
        }
        return;
    }

    const int k = blk;
    if (t == 0) lcnt = 0;
    __syncthreads();

    // Scan idx (written by k1 to out[O3]) for matches
    const float fk = (float)k;
    const float* idxf = out + O3;
    #pragma unroll 4
    for (int i = 0; i < 256; ++i) {
        int v = i * 256 + t;
        float f = idxf[v];
        if (f == fk) {
            int p = atomicAdd(&lcnt, 1);
            if (p < LISTCAP) list[p] = v;
        }
    }
    __syncthreads();
    int m = lcnt < LISTCAP ? lcnt : LISTCAP;

    // Gather + sum matching flat rows: 4 waves x 4-way ILP, lane = c
    const float* flat = wsf + WS_FLAT;
    float a[4] = {0.0f, 0.0f, 0.0f, 0.0f};
    for (int i = w * 4; i < m; i += 16) {
        #pragma unroll
        for (int j = 0; j < 4; ++j)
            if (i + j < m) a[j] += flat[list[i + j] * 64 + lane];
    }
    rpart[w][lane] = (a[0] + a[1]) + (a[2] + a[3]);
    __syncthreads();

    if (t < 64) {
        float dwv = rpart[0][t] + rpart[1][t] + rpart[2][t] + rpart[3][t];
        float countk = (float)m;
        float raw = 0.99f * ema_cs[k] + 0.01f * countk;
        float n   = wsf[WS_N];
        float cs  = (raw + 1e-5f) / (n + 512.0f * 1e-5f) * n;   // Laplace smoothing
        float wv  = 0.99f * ema_w[k * DIM + t] + 0.01f * dwv;
        out[O5 + k * DIM + t] = wv;
        out[O6 + k * DIM + t] = wv / cs;
        if (t == 0) out[O4 + k] = cs;
    }
}

extern "C" void kernel_launch(void* const* d_in, const int* in_sizes, int n_in,
                              void* d_out, int out_size, void* d_ws, size_t ws_size,
                              hipStream_t stream) {
    const float* in     = (const float*)d_in[0];   // inputs  (64,64,32,32) NCHW
    const float* emb    = (const float*)d_in[1];   // embedding (512,64)
    const float* ema_w  = (const float*)d_in[2];   // ema_w (512,64)
    const float* ema_cs = (const float*)d_in[3];   // ema_cluster_size (512)
    float* out = (float*)d_out;
    float* wsf = (float*)d_ws;

    hipLaunchKernelGGL(k0_init, dim3(387),  dim3(256), 0, stream, emb, ema_cs, wsf);
    hipLaunchKernelGGL(k1_main, dim3(2048), dim3(256), 0, stream, in, emb, out, wsf);
    hipLaunchKernelGGL(k2,      dim3(513),  dim3(256), 0, stream, ema_cs, ema_w, out, wsf);
}

// Round 4
// 311.059 us; speedup vs baseline: 1.0288x; 1.0288x over previous
//
#include <hip/hip_runtime.h>

#define K_CODES 512
#define DIM 64
#define HW 1024
#define NVEC 65536
#define NREP 4

// Output offsets (flat concat, reference return order)
#define O0 0             // loss (1)
#define O1 1             // out_q NCHW (4194304)
#define O2 4194305       // perplexity (1)
#define O3 4194306       // idx as float (65536)
#define O4 4259842       // new_cs (512)
#define O5 4260354       // new_ema_w (32768)
#define O6 4293122       // new_embedding (32768)

// ws float layout:
// [0..512)          = ee (||e_k||^2)
// [512..2560)       = counts, 4 replicas x 512 (int)
// [2560..4608)      = per-block loss partials (2048)
// [4608]            = n (0.99*sum(ema_cs) + 0.01*65536)
// [4864..5376)      = base (exclusive prefix of counts, int)
// [5376..5888)      = scatter cursors (int, zeroed in k0)
// [5888..38656)     = perm (65536 ushort, counting-sort permutation)
// [38656..4232960)  = flat x rows (65536 x 64 fp32)
// [4232960..)       = B-pack (98304 bf16, MFMA-frag order)
#define WS_EE    0
#define WS_CNT   512
#define WS_LOSS  2560
#define WS_N     4608
#define WS_BASE  4864
#define WS_CUR   5376
#define WS_PERM  5888
#define WS_FLAT  38656
#define WS_BP    4232960

#define LISTCAP 12288

typedef __bf16 bf16x8 __attribute__((ext_vector_type(8)));
typedef float  f32x4  __attribute__((ext_vector_type(4)));

__global__ void k0_init(const float* __restrict__ emb, const float* __restrict__ ema_cs,
                        float* __restrict__ wsf) {
    __shared__ float sn[256];
    const int b = blockIdx.x, t = threadIdx.x;
    if (b == 0) {
        int* cnt = (int*)(wsf + WS_CNT);
        #pragma unroll
        for (int i = 0; i < 8; ++i) cnt[i * 256 + t] = 0;   // zero 4 cnt replicas
        int* cur = (int*)(wsf + WS_CUR);
        cur[t] = 0; cur[t + 256] = 0;                        // zero scatter cursors
        sn[t] = ema_cs[t] + ema_cs[t + 256];
        __syncthreads();
        for (int s = 128; s > 0; s >>= 1) {
            if (t < s) sn[t] += sn[t + s];
            __syncthreads();
        }
        if (t == 0) wsf[WS_N] = 0.99f * sn[0] + 0.01f * 65536.0f;  // n (counts sum to NVEC)
    } else if (b < 3) {
        int k = (b - 1) * 256 + t;                       // 0..511
        const float* e = emb + k * DIM;
        float s = 0.0f;
        #pragma unroll
        for (int c = 0; c < DIM; ++c) s += e[c] * e[c];
        wsf[WS_EE + k] = s;                              // ||e_k||^2
    } else {
        // Pack bf16 3-way split of (-2*e) into MFMA B-fragment order:
        // frag(s, ntg, ks): lane l holds B^T[code = ntg*16 + (l&15)][c = ks*32 + (l>>4)*8 + j]
        int g = (b - 3) * 256 + t;                       // 0..98303
        int j    = g & 7;
        int lane = (g >> 3) & 63;
        int ks   = (g >> 9) & 1;
        int rest = g >> 10;                              // 0..95
        int ntg  = rest & 31;
        int s    = rest >> 5;                            // split 0..2
        int code = ntg * 16 + (lane & 15);
        int c    = ks * 32 + (lane >> 4) * 8 + j;
        float v = -2.0f * emb[code * DIM + c];
        __bf16 h0 = (__bf16)v;  float r1 = v  - (float)h0;
        __bf16 h1 = (__bf16)r1; float r2 = r1 - (float)h1;
        __bf16 hv = (s == 0) ? h0 : (s == 1 ? h1 : (__bf16)r2);
        ((__bf16*)(wsf + WS_BP))[g] = hv;
    }
}

// Block: 256 threads = 4 waves; 32 vectors x 512 codes per block (2048 blocks).
// Wave ni: 32-vector x 128-code tile = 2x8 MFMA 16x16 tiles, acc[2][8]=64 AGPR.
// NO fp32 atomics: x rows plain-stored to flat ws buffer; k1c/k2 do the segment-sum.
__global__ __launch_bounds__(256, 4)
void k1_main(const float* __restrict__ in, const float* __restrict__ emb,
             float* __restrict__ out, float* __restrict__ wsf) {
    __shared__ float xs[32 * 65];            // fp32 x tile, row stride 65
    __shared__ unsigned int xsp[3][32 * 36]; // bf16 splits, packed pairs; row stride 36 uints
    __shared__ float pmin[4][32];
    __shared__ int   pidx[4][32];
    __shared__ float xxs[32];
    __shared__ int   hist[K_CODES];

    const int t    = threadIdx.x;
    const int lane = t & 63;
    const int wave = t >> 6;           // 0..3
    const int ni   = wave;             // 128-code quarter
    const int col  = lane & 15;
    const int quad = lane >> 4;

    hist[t] = 0; hist[t + 256] = 0;

    const int blk     = blockIdx.x;                    // 0..2047
    const int rep     = blk & (NREP - 1);              // cnt atomic replica
    const int n_img   = blk >> 5;
    const int hw_base = (blk & 31) * 32;
    const float* xbase = in + n_img * (DIM * HW) + hw_base;

    // Stage x: 32 vectors x 64 c, coalesced global reads
    #pragma unroll
    for (int it = 0; it < 8; ++it) {
        int e = it * 256 + t;
        int c = e >> 5, h = e & 31;
        xs[h * 65 + c] = xbase[c * HW + h];
    }

    // Accumulators init with ||e||^2 (d = ee - 2<x,e>)
    f32x4 acc[2][8];
    #pragma unroll
    for (int nt = 0; nt < 8; ++nt) {
        float eev = wsf[WS_EE + ni * 128 + nt * 16 + col];
        #pragma unroll
        for (int mi = 0; mi < 2; ++mi) {
            acc[mi][nt][0] = eev; acc[mi][nt][1] = eev;
            acc[mi][nt][2] = eev; acc[mi][nt][3] = eev;
        }
    }

    __syncthreads();

    // Build bf16 3-split of x once (pairs packed into uint), + ||x||^2
    #pragma unroll
    for (int i = 0; i < 4; ++i) {
        int e = i * 256 + t;                 // 0..1023 c-pairs
        int row = e >> 5, cp = e & 31;
        float v0 = xs[row * 65 + 2 * cp];
        float v1 = xs[row * 65 + 2 * cp + 1];
        __bf16 a0 = (__bf16)v0; float ra = v0 - (float)a0;
        __bf16 a1 = (__bf16)ra; ra -= (float)a1;
        __bf16 a2 = (__bf16)ra;
        __bf16 b0 = (__bf16)v1; float rb = v1 - (float)b0;
        __bf16 b1 = (__bf16)rb; rb -= (float)b1;
        __bf16 b2 = (__bf16)rb;
        union { __bf16 h[2]; unsigned int u; } u0, u1, u2;
        u0.h[0] = a0; u0.h[1] = b0;
        u1.h[0] = a1; u1.h[1] = b1;
        u2.h[0] = a2; u2.h[1] = b2;
        xsp[0][row * 36 + cp] = u0.u;
        xsp[1][row * 36 + cp] = u1.u;
        xsp[2][row * 36 + cp] = u2.u;
    }
    if (t < 32) {
        float s = 0.0f;
        #pragma unroll
        for (int c = 0; c < DIM; ++c) { float v = xs[t * 65 + c]; s += v * v; }
        xxs[t] = s;
    }

    // flat rows for k2's gather (plain coalesced stores, fire-and-forget)
    #pragma unroll
    for (int v8 = 0; v8 < 8; ++v8) {
        int v = wave * 8 + v8;
        wsf[WS_FLAT + (blk * 32 + v) * 64 + lane] = xs[v * 65 + lane];
    }
    __syncthreads();

    const bf16x8* bp8 = (const bf16x8*)(wsf + WS_BP);

    // K-loop: 2 k-steps x 6 split-pairs {(0,0),(1,0),(2,0),(0,1),(1,1),(0,2)}
    #pragma unroll
    for (int ks = 0; ks < 2; ++ks) {
        bf16x8 A0[2], A1[2], A2[2];
        #pragma unroll
        for (int mi = 0; mi < 2; ++mi) {
            int u = (mi * 16 + col) * 36 + ks * 16 + quad * 4;
            A0[mi] = *(const bf16x8*)&xsp[0][u];
            A1[mi] = *(const bf16x8*)&xsp[1][u];
            A2[mi] = *(const bf16x8*)&xsp[2][u];
        }
        #pragma unroll
        for (int s = 0; s < 3; ++s) {
            #pragma unroll
            for (int bh = 0; bh < 2; ++bh) {
                bf16x8 Bv[4];
                #pragma unroll
                for (int n4 = 0; n4 < 4; ++n4) {
                    int nt = bh * 4 + n4;
                    Bv[n4] = bp8[(((s * 32 + ni * 8 + nt) * 2 + ks) * 64) + lane];
                }
                #pragma unroll
                for (int mi = 0; mi < 2; ++mi)
                    #pragma unroll
                    for (int n4 = 0; n4 < 4; ++n4)
                        acc[mi][bh * 4 + n4] = __builtin_amdgcn_mfma_f32_16x16x32_bf16(A0[mi], Bv[n4], acc[mi][bh * 4 + n4], 0, 0, 0);
                if (s < 2) {
                    #pragma unroll
                    for (int mi = 0; mi < 2; ++mi)
                        #pragma unroll
                        for (int n4 = 0; n4 < 4; ++n4)
                            acc[mi][bh * 4 + n4] = __builtin_amdgcn_mfma_f32_16x16x32_bf16(A1[mi], Bv[n4], acc[mi][bh * 4 + n4], 0, 0, 0);
                }
                if (s == 0) {
                    #pragma unroll
                    for (int mi = 0; mi < 2; ++mi)
                        #pragma unroll
                        for (int n4 = 0; n4 < 4; ++n4)
                            acc[mi][bh * 4 + n4] = __builtin_amdgcn_mfma_f32_16x16x32_bf16(A2[mi], Bv[n4], acc[mi][bh * 4 + n4], 0, 0, 0);
                }
            }
        }
    }

    // Argmin. C layout: col(code) = lane&15, row(vector) = quad*4 + reg.
    #pragma unroll
    for (int mi = 0; mi < 2; ++mi) {
        #pragma unroll
        for (int r = 0; r < 4; ++r) {
            float v  = acc[mi][0][r];
            int   bi = ni * 128 + col;
            #pragma unroll
            for (int nt = 1; nt < 8; ++nt) {            // ascending codes, strict < = first-min
                float u  = acc[mi][nt][r];
                int   ui = ni * 128 + nt * 16 + col;
                if (u < v) { v = u; bi = ui; }
            }
            #pragma unroll
            for (int off = 1; off < 16; off <<= 1) {    // 16-lane butterfly, idx tie-break
                float ov = __shfl_xor(v, off);
                int   oi = __shfl_xor(bi, off);
                if (ov < v || (ov == v && oi < bi)) { v = ov; bi = oi; }
            }
            if (col == 0) {
                int row = mi * 16 + quad * 4 + r;
                pmin[ni][row] = v;
                pidx[ni][row] = bi;
            }
        }
    }
    __syncthreads();

    // Combine the 4 n-quarters (ascending code ranges), then idx/loss/hist
    if (t < 32) {
        float v = pmin[0][t]; int bi = pidx[0][t];
        #pragma unroll
        for (int q = 1; q < 4; ++q) {
            float u = pmin[q][t]; int ui = pidx[q][t];
            if (u < v) { v = u; bi = ui; }
        }
        pidx[0][t] = bi;                                 // publish final idx
        out[O3 + blk * 32 + t] = (float)bi;
        atomicAdd(&hist[bi], 1);
        float ld = v + xxs[t];                           // d_min = xx + (ee - 2<x,e>)
        #pragma unroll
        for (int off = 16; off > 0; off >>= 1) ld += __shfl_down(ld, off);
        if (t == 0) wsf[WS_LOSS + blk] = ld;             // per-block loss partial
    }
    __syncthreads();

    // out_q: thread t -> vector v = t&31, c-octant t>>5; coalesced per c-plane
    {
        int v = t & 31, cq = t >> 5;
        int kv = pidx[0][v];
        const float* ew = emb + kv * DIM;
        float* oq = out + O1 + n_img * (DIM * HW) + hw_base + v;
        #pragma unroll
        for (int c = cq * 8; c < cq * 8 + 8; ++c) oq[c * HW] = ew[c];
    }

    // counts: tiny int atomics only (histogram-compacted)
    int* cnt = (int*)(wsf + WS_CNT);
    if (hist[t])       atomicAdd(&cnt[rep * 512 + t], hist[t]);
    if (hist[t + 256]) atomicAdd(&cnt[rep * 512 + t + 256], hist[t + 256]);
}

// k1c: counting-sort scatter. 64 blocks x 1024 threads = 65536 elements.
// Each block redundantly computes the exclusive prefix of the 512 counts
// (LDS scan), then scatters its indices: perm[base[k] + cursor[k]++] = v.
__global__ __launch_bounds__(1024)
void k1c_scatter(const float* __restrict__ out, float* __restrict__ wsf) {
    __shared__ int sc[512];
    const int t = threadIdx.x;
    const int* cnt = (const int*)(wsf + WS_CNT);

    int myc = 0;
    if (t < 512) {
        #pragma unroll
        for (int r = 0; r < NREP; ++r) myc += cnt[r * 512 + t];
        sc[t] = myc;
    }
    __syncthreads();
    // Hillis-Steele inclusive scan over 512 entries
    for (int off = 1; off < 512; off <<= 1) {
        int v = 0;
        if (t < 512) { v = sc[t]; if (t >= off) v += sc[t - off]; }
        __syncthreads();
        if (t < 512) sc[t] = v;
        __syncthreads();
    }
    if (t < 512) {
        int base = sc[t] - myc;                          // exclusive
        sc[t] = base;
        ((int*)(wsf + WS_BASE))[t] = base;               // publish for k2 (all blocks write same value)
    }
    __syncthreads();

    const int v = blockIdx.x * 1024 + t;                 // 0..65535
    const int k = (int)out[O3 + v];
    int* gcur = (int*)(wsf + WS_CUR);
    int pos = sc[k] + atomicAdd(&gcur[k], 1);
    ((unsigned short*)(wsf + WS_PERM))[pos] = (unsigned short)v;
}

// k2: blocks 0..511 = one code each (contiguous perm segment -> gather flat rows
// -> EMA outputs); block 512 = loss + perplexity.
__global__ void k2(const float* __restrict__ ema_cs, const float* __restrict__ ema_w,
                   float* __restrict__ out, const float* __restrict__ wsf) {
    __shared__ int   list[LISTCAP];
    __shared__ float rpart[4][64];
    __shared__ float s1[256], s2[256];
    __shared__ int   sm_m, sm_base;

    const int t = threadIdx.x;
    const int lane = t & 63;
    const int w = t >> 6;
    const int blk = blockIdx.x;

    if (blk == 512) {
        // loss: sum 2048 per-block partials
        float ls = 0.0f;
        #pragma unroll
        for (int j = 0; j < 8; ++j) ls += wsf[WS_LOSS + j * 256 + t];
        s1[t] = ls;
        // perplexity from counts
        const int* cnt = (const int*)(wsf + WS_CNT);
        float ca = 0.0f, cb = 0.0f;
        #pragma unroll
        for (int r = 0; r < NREP; ++r) {
            ca += (float)cnt[r * 512 + t];
            cb += (float)cnt[r * 512 + 256 + t];
        }
        float pa = ca * (1.0f / 65536.0f);
        float pb = cb * (1.0f / 65536.0f);
        s2[t] = pa * logf(pa + 1e-10f) + pb * logf(pb + 1e-10f);
        __syncthreads();
        for (int s = 128; s > 0; s >>= 1) {
            if (t < s) { s1[t] += s1[t + s]; s2[t] += s2[t + s]; }
            __syncthreads();
        }
        if (t == 0) {
            out[O0] = 0.25f * s1[0] * (1.0f / 4194304.0f);
            out[O2] = expf(-s2[0]);
        }
        return;
    }

    const int k = blk;
    if (t == 0) {
        const int* cnt = (const int*)(wsf + WS_CNT);
        int c = 0;
        #pragma unroll
        for (int r = 0; r < NREP; ++r) c += cnt[r * 512 + k];
        sm_m = c;
        sm_base = ((const int*)(wsf + WS_BASE))[k];
    }
    __syncthreads();
    const int m = sm_m, base = sm_base;

    // Preload perm segment into LDS (breaks load->load dependence chain)
    const unsigned short* perm = (const unsigned short*)(wsf + WS_PERM);
    for (int i = t; i < m && i < LISTCAP; i += 256) list[i] = perm[base + i];
    __syncthreads();

    // Gather + sum matching flat rows: 4 waves x 4-way ILP, lane = c
    const float* flat = wsf + WS_FLAT;
    float a[4] = {0.0f, 0.0f, 0.0f, 0.0f};
    for (int i = w * 4; i < m; i += 16) {
        #pragma unroll
        for (int j = 0; j < 4; ++j) {
            int ii = i + j;
            if (ii < m) {
                int row = (ii < LISTCAP) ? list[ii] : (int)perm[base + ii];
                a[j] += flat[row * 64 + lane];
            }
        }
    }
    rpart[w][lane] = (a[0] + a[1]) + (a[2] + a[3]);
    __syncthreads();

    if (t < 64) {
        float dwv = rpart[0][t] + rpart[1][t] + rpart[2][t] + rpart[3][t];
        float countk = (float)m;
        float raw = 0.99f * ema_cs[k] + 0.01f * countk;
        float n   = wsf[WS_N];
        float cs  = (raw + 1e-5f) / (n + 512.0f * 1e-5f) * n;   // Laplace smoothing
        float wv  = 0.99f * ema_w[k * DIM + t] + 0.01f * dwv;
        out[O5 + k * DIM + t] = wv;
        out[O6 + k * DIM + t] = wv / cs;
        if (t == 0) out[O4 + k] = cs;
    }
}

extern "C" void kernel_launch(void* const* d_in, const int* in_sizes, int n_in,
                              void* d_out, int out_size, void* d_ws, size_t ws_size,
                              hipStream_t stream) {
    const float* in     = (const float*)d_in[0];   // inputs  (64,64,32,32) NCHW
    const float* emb    = (const float*)d_in[1];   // embedding (512,64)
    const float* ema_w  = (const float*)d_in[2];   // ema_w (512,64)
    const float* ema_cs = (const float*)d_in[3];   // ema_cluster_size (512)
    float* out = (float*)d_out;
    float* wsf = (float*)d_ws;

    hipLaunchKernelGGL(k0_init,     dim3(387),  dim3(256),  0, stream, emb, ema_cs, wsf);
    hipLaunchKernelGGL(k1_main,     dim3(2048), dim3(256),  0, stream, in, emb, out, wsf);
    hipLaunchKernelGGL(k1c_scatter, dim3(64),   dim3(1024), 0, stream, out, wsf);
    hipLaunchKernelGGL(k2,          dim3(513),  dim3(256),  0, stream, ema_cs, ema_w, out, wsf);
}

// Round 5
// 169.452 us; speedup vs baseline: 1.8885x; 1.8357x over previous
//
#include <hip/hip_runtime.h>

#define K_CODES 512
#define DIM 64
#define HW 1024
#define NVEC 65536
#define NREP 4

// Output offsets (flat concat, reference return order)
#define O0 0             // loss (1)
#define O1 1             // out_q NCHW (4194304)
#define O2 4194305       // perplexity (1)
#define O3 4194306       // idx as float (65536)
#define O4 4259842       // new_cs (512)
#define O5 4260354       // new_ema_w (32768)
#define O6 4293122       // new_embedding (32768)

// ws float layout:
// [0..512)            = ee (||e_k||^2)
// [512..2560)         = counts, 4 replicas x 512 (int)
// [2560..4608)        = per-block loss partials (2048)
// [4608]              = n (0.99*sum(ema_cs) + 0.01*65536)
// [4864..5376)        = base (exclusive prefix of counts, int)
// [5376..5888)        = scatter cursors (int)
// [5888..38656)       = perm (65536 ushort, counting-sort permutation)
// [38656..71424)      = code (65536 ushort, sorted code per position)
// [71424..104192)     = dw (512 x 64 fp32)
// [104192..4298496)   = flat x rows (65536 x 64 fp32)
// [4298496..)         = B-pack (98304 bf16, MFMA-frag order)
#define WS_EE    0
#define WS_CNT   512
#define WS_LOSS  2560
#define WS_N     4608
#define WS_BASE  4864
#define WS_CUR   5376
#define WS_PERM  5888
#define WS_CODE  38656
#define WS_DW    71424
#define WS_FLAT  104192
#define WS_BP    4298496

typedef __bf16 bf16x8 __attribute__((ext_vector_type(8)));
typedef float  f32x4  __attribute__((ext_vector_type(4)));

__global__ void k0_init(const float* __restrict__ emb, const float* __restrict__ ema_cs,
                        float* __restrict__ wsf) {
    __shared__ float sn[256];
    const int b = blockIdx.x, t = threadIdx.x;
    if (b < 128) {
        wsf[WS_DW + b * 256 + t] = 0.0f;                 // zero dw
    } else if (b == 128) {
        int* cnt = (int*)(wsf + WS_CNT);
        #pragma unroll
        for (int i = 0; i < 8; ++i) cnt[i * 256 + t] = 0;   // zero 4 cnt replicas
        int* cur = (int*)(wsf + WS_CUR);
        cur[t] = 0; cur[t + 256] = 0;                        // zero scatter cursors
        sn[t] = ema_cs[t] + ema_cs[t + 256];
        __syncthreads();
        for (int s = 128; s > 0; s >>= 1) {
            if (t < s) sn[t] += sn[t + s];
            __syncthreads();
        }
        if (t == 0) wsf[WS_N] = 0.99f * sn[0] + 0.01f * 65536.0f;  // n (counts sum to NVEC)
    } else if (b < 131) {
        int k = (b - 129) * 256 + t;                     // 0..511
        const float* e = emb + k * DIM;
        float s = 0.0f;
        #pragma unroll
        for (int c = 0; c < DIM; ++c) s += e[c] * e[c];
        wsf[WS_EE + k] = s;                              // ||e_k||^2
    } else {
        // Pack bf16 3-way split of (-2*e) into MFMA B-fragment order:
        // frag(s, ntg, ks): lane l holds B^T[code = ntg*16 + (l&15)][c = ks*32 + (l>>4)*8 + j]
        int g = (b - 131) * 256 + t;                     // 0..98303
        int j    = g & 7;
        int lane = (g >> 3) & 63;
        int ks   = (g >> 9) & 1;
        int rest = g >> 10;                              // 0..95
        int ntg  = rest & 31;
        int s    = rest >> 5;                            // split 0..2
        int code = ntg * 16 + (lane & 15);
        int c    = ks * 32 + (lane >> 4) * 8 + j;
        float v = -2.0f * emb[code * DIM + c];
        __bf16 h0 = (__bf16)v;  float r1 = v  - (float)h0;
        __bf16 h1 = (__bf16)r1; float r2 = r1 - (float)h1;
        __bf16 hv = (s == 0) ? h0 : (s == 1 ? h1 : (__bf16)r2);
        ((__bf16*)(wsf + WS_BP))[g] = hv;
    }
}

// Block: 256 threads = 4 waves; 32 vectors x 512 codes per block (2048 blocks).
// Wave ni: 32-vector x 128-code tile = 2x8 MFMA 16x16 tiles, acc[2][8]=64 AGPR.
__global__ __launch_bounds__(256, 4)
void k1_main(const float* __restrict__ in, const float* __restrict__ emb,
             float* __restrict__ out, float* __restrict__ wsf) {
    __shared__ float xs[32 * 65];            // fp32 x tile, row stride 65
    __shared__ unsigned int xsp[3][32 * 36]; // bf16 splits, packed pairs; row stride 36 uints
    __shared__ float pmin[4][32];
    __shared__ int   pidx[4][32];
    __shared__ float xxs[32];
    __shared__ int   hist[K_CODES];

    const int t    = threadIdx.x;
    const int lane = t & 63;
    const int wave = t >> 6;           // 0..3
    const int ni   = wave;             // 128-code quarter
    const int col  = lane & 15;
    const int quad = lane >> 4;

    hist[t] = 0; hist[t + 256] = 0;

    const int blk     = blockIdx.x;                    // 0..2047
    const int rep     = blk & (NREP - 1);              // cnt atomic replica
    const int n_img   = blk >> 5;
    const int hw_base = (blk & 31) * 32;
    const float* xbase = in + n_img * (DIM * HW) + hw_base;

    // Stage x: 32 vectors x 64 c, coalesced global reads
    #pragma unroll
    for (int it = 0; it < 8; ++it) {
        int e = it * 256 + t;
        int c = e >> 5, h = e & 31;
        xs[h * 65 + c] = xbase[c * HW + h];
    }

    // Accumulators init with ||e||^2 (d = ee - 2<x,e>)
    f32x4 acc[2][8];
    #pragma unroll
    for (int nt = 0; nt < 8; ++nt) {
        float eev = wsf[WS_EE + ni * 128 + nt * 16 + col];
        #pragma unroll
        for (int mi = 0; mi < 2; ++mi) {
            acc[mi][nt][0] = eev; acc[mi][nt][1] = eev;
            acc[mi][nt][2] = eev; acc[mi][nt][3] = eev;
        }
    }

    __syncthreads();

    // Build bf16 3-split of x once (pairs packed into uint), + ||x||^2
    #pragma unroll
    for (int i = 0; i < 4; ++i) {
        int e = i * 256 + t;                 // 0..1023 c-pairs
        int row = e >> 5, cp = e & 31;
        float v0 = xs[row * 65 + 2 * cp];
        float v1 = xs[row * 65 + 2 * cp + 1];
        __bf16 a0 = (__bf16)v0; float ra = v0 - (float)a0;
        __bf16 a1 = (__bf16)ra; ra -= (float)a1;
        __bf16 a2 = (__bf16)ra;
        __bf16 b0 = (__bf16)v1; float rb = v1 - (float)b0;
        __bf16 b1 = (__bf16)rb; rb -= (float)b1;
        __bf16 b2 = (__bf16)rb;
        union { __bf16 h[2]; unsigned int u; } u0, u1, u2;
        u0.h[0] = a0; u0.h[1] = b0;
        u1.h[0] = a1; u1.h[1] = b1;
        u2.h[0] = a2; u2.h[1] = b2;
        xsp[0][row * 36 + cp] = u0.u;
        xsp[1][row * 36 + cp] = u1.u;
        xsp[2][row * 36 + cp] = u2.u;
    }
    if (t < 32) {
        float s = 0.0f;
        #pragma unroll
        for (int c = 0; c < DIM; ++c) { float v = xs[t * 65 + c]; s += v * v; }
        xxs[t] = s;
    }

    // flat rows for k2a's gather (plain coalesced stores, fire-and-forget)
    #pragma unroll
    for (int v8 = 0; v8 < 8; ++v8) {
        int v = wave * 8 + v8;
        wsf[WS_FLAT + (blk * 32 + v) * 64 + lane] = xs[v * 65 + lane];
    }
    __syncthreads();

    const bf16x8* bp8 = (const bf16x8*)(wsf + WS_BP);

    // K-loop: 2 k-steps x 6 split-pairs {(0,0),(1,0),(2,0),(0,1),(1,1),(0,2)}
    #pragma unroll
    for (int ks = 0; ks < 2; ++ks) {
        bf16x8 A0[2], A1[2], A2[2];
        #pragma unroll
        for (int mi = 0; mi < 2; ++mi) {
            int u = (mi * 16 + col) * 36 + ks * 16 + quad * 4;
            A0[mi] = *(const bf16x8*)&xsp[0][u];
            A1[mi] = *(const bf16x8*)&xsp[1][u];
            A2[mi] = *(const bf16x8*)&xsp[2][u];
        }
        #pragma unroll
        for (int s = 0; s < 3; ++s) {
            #pragma unroll
            for (int bh = 0; bh < 2; ++bh) {
                bf16x8 Bv[4];
                #pragma unroll
                for (int n4 = 0; n4 < 4; ++n4) {
                    int nt = bh * 4 + n4;
                    Bv[n4] = bp8[(((s * 32 + ni * 8 + nt) * 2 + ks) * 64) + lane];
                }
                #pragma unroll
                for (int mi = 0; mi < 2; ++mi)
                    #pragma unroll
                    for (int n4 = 0; n4 < 4; ++n4)
                        acc[mi][bh * 4 + n4] = __builtin_amdgcn_mfma_f32_16x16x32_bf16(A0[mi], Bv[n4], acc[mi][bh * 4 + n4], 0, 0, 0);
                if (s < 2) {
                    #pragma unroll
                    for (int mi = 0; mi < 2; ++mi)
                        #pragma unroll
                        for (int n4 = 0; n4 < 4; ++n4)
                            acc[mi][bh * 4 + n4] = __builtin_amdgcn_mfma_f32_16x16x32_bf16(A1[mi], Bv[n4], acc[mi][bh * 4 + n4], 0, 0, 0);
                }
                if (s == 0) {
                    #pragma unroll
                    for (int mi = 0; mi < 2; ++mi)
                        #pragma unroll
                        for (int n4 = 0; n4 < 4; ++n4)
                            acc[mi][bh * 4 + n4] = __builtin_amdgcn_mfma_f32_16x16x32_bf16(A2[mi], Bv[n4], acc[mi][bh * 4 + n4], 0, 0, 0);
                }
            }
        }
    }

    // Argmin. C layout: col(code) = lane&15, row(vector) = quad*4 + reg.
    #pragma unroll
    for (int mi = 0; mi < 2; ++mi) {
        #pragma unroll
        for (int r = 0; r < 4; ++r) {
            float v  = acc[mi][0][r];
            int   bi = ni * 128 + col;
            #pragma unroll
            for (int nt = 1; nt < 8; ++nt) {            // ascending codes, strict < = first-min
                float u  = acc[mi][nt][r];
                int   ui = ni * 128 + nt * 16 + col;
                if (u < v) { v = u; bi = ui; }
            }
            #pragma unroll
            for (int off = 1; off < 16; off <<= 1) {    // 16-lane butterfly, idx tie-break
                float ov = __shfl_xor(v, off);
                int   oi = __shfl_xor(bi, off);
                if (ov < v || (ov == v && oi < bi)) { v = ov; bi = oi; }
            }
            if (col == 0) {
                int row = mi * 16 + quad * 4 + r;
                pmin[ni][row] = v;
                pidx[ni][row] = bi;
            }
        }
    }
    __syncthreads();

    // Combine the 4 n-quarters (ascending code ranges), then idx/loss/hist
    if (t < 32) {
        float v = pmin[0][t]; int bi = pidx[0][t];
        #pragma unroll
        for (int q = 1; q < 4; ++q) {
            float u = pmin[q][t]; int ui = pidx[q][t];
            if (u < v) { v = u; bi = ui; }
        }
        pidx[0][t] = bi;                                 // publish final idx
        out[O3 + blk * 32 + t] = (float)bi;
        atomicAdd(&hist[bi], 1);
        float ld = v + xxs[t];                           // d_min = xx + (ee - 2<x,e>)
        #pragma unroll
        for (int off = 16; off > 0; off >>= 1) ld += __shfl_down(ld, off);
        if (t == 0) wsf[WS_LOSS + blk] = ld;             // per-block loss partial
    }
    __syncthreads();

    // out_q: thread t -> vector v = t&31, c-octant t>>5; coalesced per c-plane
    {
        int v = t & 31, cq = t >> 5;
        int kv = pidx[0][v];
        const float* ew = emb + kv * DIM;
        float* oq = out + O1 + n_img * (DIM * HW) + hw_base + v;
        #pragma unroll
        for (int c = cq * 8; c < cq * 8 + 8; ++c) oq[c * HW] = ew[c];
    }

    // counts: tiny int atomics only (histogram-compacted)
    int* cnt = (int*)(wsf + WS_CNT);
    if (hist[t])       atomicAdd(&cnt[rep * 512 + t], hist[t]);
    if (hist[t + 256]) atomicAdd(&cnt[rep * 512 + t + 256], hist[t + 256]);
}

// k1c: counting-sort scatter. 64 blocks x 1024 threads = 65536 elements.
// Each block redundantly computes the exclusive prefix of the 512 counts
// (LDS scan), then scatters: perm[pos] = v, code[pos] = k (both sorted by k).
__global__ __launch_bounds__(1024)
void k1c_scatter(const float* __restrict__ out, float* __restrict__ wsf) {
    __shared__ int sc[512];
    const int t = threadIdx.x;
    const int* cnt = (const int*)(wsf + WS_CNT);

    int myc = 0;
    if (t < 512) {
        #pragma unroll
        for (int r = 0; r < NREP; ++r) myc += cnt[r * 512 + t];
        sc[t] = myc;
    }
    __syncthreads();
    // Hillis-Steele inclusive scan over 512 entries
    for (int off = 1; off < 512; off <<= 1) {
        int v = 0;
        if (t < 512) { v = sc[t]; if (t >= off) v += sc[t - off]; }
        __syncthreads();
        if (t < 512) sc[t] = v;
        __syncthreads();
    }
    if (t < 512) sc[t] -= myc;                           // exclusive
    __syncthreads();

    const int v = blockIdx.x * 1024 + t;                 // 0..65535
    const int k = (int)out[O3 + v];
    int* gcur = (int*)(wsf + WS_CUR);
    int pos = sc[k] + atomicAdd(&gcur[k], 1);
    ((unsigned short*)(wsf + WS_PERM))[pos] = (unsigned short)v;
    ((unsigned short*)(wsf + WS_CODE))[pos] = (unsigned short)k;
}

// k2a: skew-proof segment-sum. 1024 blocks x 256 thr; block b owns sorted perm
// window [b*64, b*64+64); wave w handles 16 rows with run-accumulation and one
// atomic row-flush per code change (total flushes <= 512 + 4096).
__global__ __launch_bounds__(256)
void k2a_gather(float* __restrict__ wsf) {
    __shared__ unsigned short lperm[64];
    __shared__ unsigned short lcode[64];
    const int t = threadIdx.x;
    const int lane = t & 63;
    const int w = t >> 6;
    const int b = blockIdx.x;

    if (t < 64) {
        lperm[t] = ((const unsigned short*)(wsf + WS_PERM))[b * 64 + t];
        lcode[t] = ((const unsigned short*)(wsf + WS_CODE))[b * 64 + t];
    }
    __syncthreads();

    const float* flat = wsf + WS_FLAT;
    float* dw = wsf + WS_DW;
    const int i0 = w * 16;

    float acc = 0.0f;
    int curk = lcode[i0];
    float nxt = flat[(int)lperm[i0] * 64 + lane];        // 1-deep prefetch
    #pragma unroll
    for (int r = 0; r < 16; ++r) {
        float v = nxt;
        if (r < 15) nxt = flat[(int)lperm[i0 + r + 1] * 64 + lane];
        int k = lcode[i0 + r];
        if (k != curk) {                                  // wave-uniform
            atomicAdd(&dw[curk * 64 + lane], acc);
            acc = 0.0f; curk = k;
        }
        acc += v;
    }
    atomicAdd(&dw[curk * 64 + lane], acc);
}

// k2b: EMA epilogue. Blocks 0..127: new_ema_w / new_embedding / new_cs
// (coalesced); block 128: loss + perplexity.
__global__ void k2b(const float* __restrict__ ema_cs, const float* __restrict__ ema_w,
                    float* __restrict__ out, const float* __restrict__ wsf) {
    __shared__ float s1[256], s2[256];
    const int t = threadIdx.x;
    const int blk = blockIdx.x;
    const int* cnt = (const int*)(wsf + WS_CNT);

    if (blk == 128) {
        // loss: sum 2048 per-block partials
        float ls = 0.0f;
        #pragma unroll
        for (int j = 0; j < 8; ++j) ls += wsf[WS_LOSS + j * 256 + t];
        s1[t] = ls;
        // perplexity from counts
        float ca = 0.0f, cb = 0.0f;
        #pragma unroll
        for (int r = 0; r < NREP; ++r) {
            ca += (float)cnt[r * 512 + t];
            cb += (float)cnt[r * 512 + 256 + t];
        }
        float pa = ca * (1.0f / 65536.0f);
        float pb = cb * (1.0f / 65536.0f);
        s2[t] = pa * logf(pa + 1e-10f) + pb * logf(pb + 1e-10f);
        __syncthreads();
        for (int s = 128; s > 0; s >>= 1) {
            if (t < s) { s1[t] += s1[t + s]; s2[t] += s2[t + s]; }
            __syncthreads();
        }
        if (t == 0) {
            out[O0] = 0.25f * s1[0] * (1.0f / 4194304.0f);
            out[O2] = expf(-s2[0]);
        }
        return;
    }

    const int m = blk * 256 + t;                         // 0..32767
    const int k = m >> 6;
    float ck = 0.0f;
    #pragma unroll
    for (int r = 0; r < NREP; ++r) ck += (float)cnt[r * 512 + k];
    float n    = wsf[WS_N];
    float rawk = 0.99f * ema_cs[k] + 0.01f * ck;
    float csk  = (rawk + 1e-5f) / (n + 512.0f * 1e-5f) * n;   // Laplace smoothing
    float wv   = 0.99f * ema_w[m] + 0.01f * wsf[WS_DW + m];
    out[O5 + m] = wv;
    out[O6 + m] = wv / csk;
    if ((m & 63) == 0) out[O4 + k] = csk;
}

extern "C" void kernel_launch(void* const* d_in, const int* in_sizes, int n_in,
                              void* d_out, int out_size, void* d_ws, size_t ws_size,
                              hipStream_t stream) {
    const float* in     = (const float*)d_in[0];   // inputs  (64,64,32,32) NCHW
    const float* emb    = (const float*)d_in[1];   // embedding (512,64)
    const float* ema_w  = (const float*)d_in[2];   // ema_w (512,64)
    const float* ema_cs = (const float*)d_in[3];   // ema_cluster_size (512)
    float* out = (float*)d_out;
    float* wsf = (float*)d_ws;

    hipLaunchKernelGGL(k0_init,     dim3(515),  dim3(256),  0, stream, emb, ema_cs, wsf);
    hipLaunchKernelGGL(k1_main,     dim3(2048), dim3(256),  0, stream, in, emb, out, wsf);
    hipLaunchKernelGGL(k1c_scatter, dim3(64),   dim3(1024), 0, stream, out, wsf);
    hipLaunchKernelGGL(k2a_gather,  dim3(1024), dim3(256),  0, stream, wsf);
    hipLaunchKernelGGL(k2b,         dim3(129),  dim3(256),  0, stream, ema_cs, ema_w, out, wsf);
}

// Round 6
// 138.999 us; speedup vs baseline: 2.3023x; 1.2191x over previous
//
#include <hip/hip_runtime.h>

#define K_CODES 512
#define DIM 64
#define HW 1024
#define NVEC 65536
#define NREP 8

// Output offsets (flat concat, reference return order)
#define O0 0             // loss (1)
#define O1 1             // out_q NCHW (4194304)
#define O2 4194305       // perplexity (1)
#define O3 4194306       // idx as float (65536)
#define O4 4259842       // new_cs (512)
#define O5 4260354       // new_ema_w (32768)
#define O6 4293122       // new_embedding (32768)

// ws float layout:
// [0..512)          = ee (||e_k||^2)
// [512..4608)       = counts, 8 replicas x 512 (int)
// [4608..6656)      = per-block loss partials (2048)
// [6656]            = n (0.99*sum(ema_cs) + 0.01*65536)
// [6912..269056)    = dw, 8 replicas x 32768 (XCD-local via blk&7)
// [269056..)        = B-pack (98304 bf16, MFMA-frag order)
#define WS_EE   0
#define WS_CNT  512
#define WS_LOSS 4608
#define WS_N    6656
#define WS_DW   6912
#define WS_BP   269056

typedef __bf16 bf16x8 __attribute__((ext_vector_type(8)));
typedef float  f32x4  __attribute__((ext_vector_type(4)));

union U2 { unsigned int u; unsigned short us[2]; __bf16 h[2]; };

__global__ void k0_init(const float* __restrict__ emb, const float* __restrict__ ema_cs,
                        float* __restrict__ wsf) {
    __shared__ float sn[256];
    const int b = blockIdx.x, t = threadIdx.x;
    if (b < 128) {
        #pragma unroll
        for (int i = 0; i < 8; ++i)                      // zero 8 dw replicas (2048 f/block)
            wsf[WS_DW + b * 2048 + i * 256 + t] = 0.0f;
    } else if (b == 128) {
        int* cnt = (int*)(wsf + WS_CNT);
        #pragma unroll
        for (int i = 0; i < 16; ++i) cnt[i * 256 + t] = 0;  // zero 8 cnt replicas
        sn[t] = ema_cs[t] + ema_cs[t + 256];
        __syncthreads();
        for (int s = 128; s > 0; s >>= 1) {
            if (t < s) sn[t] += sn[t + s];
            __syncthreads();
        }
        if (t == 0) wsf[WS_N] = 0.99f * sn[0] + 0.01f * 65536.0f;  // n (counts sum to NVEC)
    } else if (b < 131) {
        int k = (b - 129) * 256 + t;                     // 0..511
        const float* e = emb + k * DIM;
        float s = 0.0f;
        #pragma unroll
        for (int c = 0; c < DIM; ++c) s += e[c] * e[c];
        wsf[WS_EE + k] = s;                              // ||e_k||^2
    } else {
        // Pack bf16 3-way split of (-2*e) into MFMA B-fragment order:
        // frag(s, ntg, ks): lane l holds B^T[code = ntg*16 + (l&15)][c = ks*32 + (l>>4)*8 + j]
        int g = (b - 131) * 256 + t;                     // 0..98303
        int j    = g & 7;
        int lane = (g >> 3) & 63;
        int ks   = (g >> 9) & 1;
        int rest = g >> 10;                              // 0..95
        int ntg  = rest & 31;
        int s    = rest >> 5;                            // split 0..2
        int code = ntg * 16 + (lane & 15);
        int c    = ks * 32 + (lane >> 4) * 8 + j;
        float v = -2.0f * emb[code * DIM + c];
        __bf16 h0 = (__bf16)v;  float r1 = v  - (float)h0;
        __bf16 h1 = (__bf16)r1; float r2 = r1 - (float)h1;
        __bf16 hv = (s == 0) ? h0 : (s == 1 ? h1 : (__bf16)r2);
        ((__bf16*)(wsf + WS_BP))[g] = hv;
    }
}

// Block: 256 threads = 4 waves; 32 vectors x 512 codes per block (2048 blocks).
// Wave ni: 32-vector x 128-code tile = 2x8 MFMA 16x16 tiles, acc[2][8]=64 AGPR.
// x is staged as column-pairs straight into the bf16 3-split LDS tile (no fp32
// x tile); dw values reconstructed from splits (error ~x*2^-24).
__global__ __launch_bounds__(256, 4)
void k1_main(const float* __restrict__ in, const float* __restrict__ emb,
             float* __restrict__ out, float* __restrict__ wsf) {
    __shared__ unsigned int xsp[3][32 * 36]; // bf16 splits, packed pairs; row stride 36 uints
    __shared__ float xxp[32][9];             // per-thread ||x||^2 partials (pad 9: bank-safe)
    __shared__ float pmin[4][32];
    __shared__ int   pidx[4][32];
    __shared__ float xxs[32];
    __shared__ int   hist[K_CODES];

    const int t    = threadIdx.x;
    const int lane = t & 63;
    const int wave = t >> 6;           // 0..3
    const int ni   = wave;             // 128-code quarter
    const int col  = lane & 15;
    const int quad = lane >> 4;

    hist[t] = 0; hist[t + 256] = 0;

    const int blk     = blockIdx.x;                    // 0..2047
    const int rep     = blk & (NREP - 1);              // XCD-local atomic replica
    const int n_img   = blk >> 5;
    const int hw_base = (blk & 31) * 32;
    const float* xbase = in + n_img * (DIM * HW) + hw_base;

    // Accumulators init with ||e||^2 (d = ee - 2<x,e>)
    f32x4 acc[2][8];
    #pragma unroll
    for (int nt = 0; nt < 8; ++nt) {
        float eev = wsf[WS_EE + ni * 128 + nt * 16 + col];
        #pragma unroll
        for (int mi = 0; mi < 2; ++mi) {
            acc[mi][nt][0] = eev; acc[mi][nt][1] = eev;
            acc[mi][nt][2] = eev; acc[mi][nt][3] = eev;
        }
    }

    // Fused stage + bf16 3-split build: thread t owns row h = t&31, column
    // pairs cp = it*8 + (t>>5). Coalesced 128B global reads per half-wave.
    {
        const int h   = t & 31;
        const int cp0 = t >> 5;
        float xxa = 0.0f;
        #pragma unroll
        for (int it = 0; it < 4; ++it) {
            int cp = it * 8 + cp0;
            float v0 = xbase[(2 * cp) * HW + h];
            float v1 = xbase[(2 * cp + 1) * HW + h];
            __bf16 a0 = (__bf16)v0; float ra = v0 - (float)a0;
            __bf16 a1 = (__bf16)ra; ra -= (float)a1;
            __bf16 a2 = (__bf16)ra;
            __bf16 b0 = (__bf16)v1; float rb = v1 - (float)b0;
            __bf16 b1 = (__bf16)rb; rb -= (float)b1;
            __bf16 b2 = (__bf16)rb;
            U2 u0, u1, u2;
            u0.h[0] = a0; u0.h[1] = b0;
            u1.h[0] = a1; u1.h[1] = b1;
            u2.h[0] = a2; u2.h[1] = b2;
            xsp[0][h * 36 + cp] = u0.u;
            xsp[1][h * 36 + cp] = u1.u;
            xsp[2][h * 36 + cp] = u2.u;
            xxa += v0 * v0 + v1 * v1;
        }
        xxp[h][cp0] = xxa;
    }
    __syncthreads();

    // ||x||^2 per vector (runs concurrent with K-loop start; read post-sync)
    if (t < 32) {
        float s = 0.0f;
        #pragma unroll
        for (int j = 0; j < 8; ++j) s += xxp[t][j];
        xxs[t] = s;
    }

    const bf16x8* bp8 = (const bf16x8*)(wsf + WS_BP);

    // K-loop: 2 k-steps x 6 split-pairs {(0,0),(1,0),(2,0),(0,1),(1,1),(0,2)}
    #pragma unroll
    for (int ks = 0; ks < 2; ++ks) {
        bf16x8 A0[2], A1[2], A2[2];
        #pragma unroll
        for (int mi = 0; mi < 2; ++mi) {
            int u = (mi * 16 + col) * 36 + ks * 16 + quad * 4;
            A0[mi] = *(const bf16x8*)&xsp[0][u];
            A1[mi] = *(const bf16x8*)&xsp[1][u];
            A2[mi] = *(const bf16x8*)&xsp[2][u];
        }
        #pragma unroll
        for (int s = 0; s < 3; ++s) {
            #pragma unroll
            for (int bh = 0; bh < 2; ++bh) {
                bf16x8 Bv[4];
                #pragma unroll
                for (int n4 = 0; n4 < 4; ++n4) {
                    int nt = bh * 4 + n4;
                    Bv[n4] = bp8[(((s * 32 + ni * 8 + nt) * 2 + ks) * 64) + lane];
                }
                #pragma unroll
                for (int mi = 0; mi < 2; ++mi)
                    #pragma unroll
                    for (int n4 = 0; n4 < 4; ++n4)
                        acc[mi][bh * 4 + n4] = __builtin_amdgcn_mfma_f32_16x16x32_bf16(A0[mi], Bv[n4], acc[mi][bh * 4 + n4], 0, 0, 0);
                if (s < 2) {
                    #pragma unroll
                    for (int mi = 0; mi < 2; ++mi)
                        #pragma unroll
                        for (int n4 = 0; n4 < 4; ++n4)
                            acc[mi][bh * 4 + n4] = __builtin_amdgcn_mfma_f32_16x16x32_bf16(A1[mi], Bv[n4], acc[mi][bh * 4 + n4], 0, 0, 0);
                }
                if (s == 0) {
                    #pragma unroll
                    for (int mi = 0; mi < 2; ++mi)
                        #pragma unroll
                        for (int n4 = 0; n4 < 4; ++n4)
                            acc[mi][bh * 4 + n4] = __builtin_amdgcn_mfma_f32_16x16x32_bf16(A2[mi], Bv[n4], acc[mi][bh * 4 + n4], 0, 0, 0);
                }
            }
        }
    }

    // Argmin. C layout: col(code) = lane&15, row(vector) = quad*4 + reg.
    #pragma unroll
    for (int mi = 0; mi < 2; ++mi) {
        #pragma unroll
        for (int r = 0; r < 4; ++r) {
            float v  = acc[mi][0][r];
            int   bi = ni * 128 + col;
            #pragma unroll
            for (int nt = 1; nt < 8; ++nt) {            // ascending codes, strict < = first-min
                float u  = acc[mi][nt][r];
                int   ui = ni * 128 + nt * 16 + col;
                if (u < v) { v = u; bi = ui; }
            }
            #pragma unroll
            for (int off = 1; off < 16; off <<= 1) {    // 16-lane butterfly, idx tie-break
                float ov = __shfl_xor(v, off);
                int   oi = __shfl_xor(bi, off);
                if (ov < v || (ov == v && oi < bi)) { v = ov; bi = oi; }
            }
            if (col == 0) {
                int row = mi * 16 + quad * 4 + r;
                pmin[ni][row] = v;
                pidx[ni][row] = bi;
            }
        }
    }
    __syncthreads();

    // Combine the 4 n-quarters (ascending code ranges), then idx/loss/hist
    if (t < 32) {
        float v = pmin[0][t]; int bi = pidx[0][t];
        #pragma unroll
        for (int q = 1; q < 4; ++q) {
            float u = pmin[q][t]; int ui = pidx[q][t];
            if (u < v) { v = u; bi = ui; }
        }
        pidx[0][t] = bi;                                 // publish final idx
        out[O3 + blk * 32 + t] = (float)bi;
        atomicAdd(&hist[bi], 1);
        float ld = v + xxs[t];                           // d_min = xx + (ee - 2<x,e>)
        #pragma unroll
        for (int off = 16; off > 0; off >>= 1) ld += __shfl_down(ld, off);
        if (t == 0) wsf[WS_LOSS + blk] = ld;             // per-block loss partial
    }
    __syncthreads();

    // out_q: thread t -> vector v = t&31, c-octant t>>5; coalesced per c-plane
    {
        int v = t & 31, cq = t >> 5;
        int kv = pidx[0][v];
        const float* ew = emb + kv * DIM;
        float* oq = out + O1 + n_img * (DIM * HW) + hw_base + v;
        #pragma unroll
        for (int c = cq * 8; c < cq * 8 + 8; ++c) oq[c * HW] = ew[c];
    }

    // dw: wave w -> rows [w*8, w*8+8); value reconstructed from the 3 splits
    // (exact to ~2^-24); coalesced 64-lane atomic row adds into XCD-local replica
    {
        float* dwr = wsf + WS_DW + rep * 32768;
        #pragma unroll 1
        for (int v8 = 0; v8 < 8; ++v8) {
            int v  = wave * 8 + v8;
            int kv = pidx[0][v];
            int wi = v * 36 + (lane >> 1);
            U2 a0, a1, a2;
            a0.u = xsp[0][wi]; a1.u = xsp[1][wi]; a2.u = xsp[2][wi];
            int hs = lane & 1;
            float val = (float)a0.h[hs] + (float)a1.h[hs] + (float)a2.h[hs];
            atomicAdd(&dwr[kv * 64 + lane], val);
        }
    }

    // counts: tiny int atomics (histogram-compacted, XCD-local replica)
    int* cnt = (int*)(wsf + WS_CNT);
    if (hist[t])       atomicAdd(&cnt[rep * 512 + t], hist[t]);
    if (hist[t + 256]) atomicAdd(&cnt[rep * 512 + t + 256], hist[t + 256]);
}

// Merged epilogue: blocks 0..127 = new_ema_w / new_embedding / new_cs (coalesced);
// block 128 = loss + perplexity.
__global__ void k2(const float* __restrict__ ema_cs, const float* __restrict__ ema_w,
                   float* __restrict__ out, const float* __restrict__ wsf) {
    __shared__ float s1[256], s2[256];
    const int t = threadIdx.x;
    const int blk = blockIdx.x;
    const int* cnt = (const int*)(wsf + WS_CNT);

    if (blk == 128) {
        // loss: sum 2048 per-block partials
        float ls = 0.0f;
        #pragma unroll
        for (int j = 0; j < 8; ++j) ls += wsf[WS_LOSS + j * 256 + t];
        s1[t] = ls;
        // perplexity from counts
        float ca = 0.0f, cb = 0.0f;
        #pragma unroll
        for (int r = 0; r < NREP; ++r) {
            ca += (float)cnt[r * 512 + t];
            cb += (float)cnt[r * 512 + 256 + t];
        }
        float pa = ca * (1.0f / 65536.0f);
        float pb = cb * (1.0f / 65536.0f);
        s2[t] = pa * logf(pa + 1e-10f) + pb * logf(pb + 1e-10f);
        __syncthreads();
        for (int s = 128; s > 0; s >>= 1) {
            if (t < s) { s1[t] += s1[t + s]; s2[t] += s2[t + s]; }
            __syncthreads();
        }
        if (t == 0) {
            out[O0] = 0.25f * s1[0] * (1.0f / 4194304.0f);
            out[O2] = expf(-s2[0]);
        }
        return;
    }

    const int m = blk * 256 + t;                         // 0..32767
    const int k = m >> 6;
    float ck = 0.0f, dwsum = 0.0f;
    #pragma unroll
    for (int r = 0; r < NREP; ++r) {
        ck    += (float)cnt[r * 512 + k];
        dwsum += wsf[WS_DW + r * 32768 + m];
    }
    float n    = wsf[WS_N];
    float rawk = 0.99f * ema_cs[k] + 0.01f * ck;
    float csk  = (rawk + 1e-5f) / (n + 512.0f * 1e-5f) * n;   // Laplace smoothing
    float wv   = 0.99f * ema_w[m] + 0.01f * dwsum;
    out[O5 + m] = wv;
    out[O6 + m] = wv / csk;
    if ((m & 63) == 0) out[O4 + k] = csk;
}

extern "C" void kernel_launch(void* const* d_in, const int* in_sizes, int n_in,
                              void* d_out, int out_size, void* d_ws, size_t ws_size,
                              hipStream_t stream) {
    const float* in     = (const float*)d_in[0];   // inputs  (64,64,32,32) NCHW
    const float* emb    = (const float*)d_in[1];   // embedding (512,64)
    const float* ema_w  = (const float*)d_in[2];   // ema_w (512,64)
    const float* ema_cs = (const float*)d_in[3];   // ema_cluster_size (512)
    float* out = (float*)d_out;
    float* wsf = (float*)d_ws;

    hipLaunchKernelGGL(k0_init, dim3(515),  dim3(256), 0, stream, emb, ema_cs, wsf);
    hipLaunchKernelGGL(k1_main, dim3(2048), dim3(256), 0, stream, in, emb, out, wsf);
    hipLaunchKernelGGL(k2,      dim3(129),  dim3(256), 0, stream, ema_cs, ema_w, out, wsf);
}

// Round 7
// 138.650 us; speedup vs baseline: 2.3081x; 1.0025x over previous
//
#include <hip/hip_runtime.h>

#define K_CODES 512
#define DIM 64
#define HW 1024
#define NVEC 65536
#define NREP 8

// Output offsets (flat concat, reference return order)
#define O0 0             // loss (1)
#define O1 1             // out_q NCHW (4194304)
#define O2 4194305       // perplexity (1)
#define O3 4194306       // idx as float (65536)
#define O4 4259842       // new_cs (512)
#define O5 4260354       // new_ema_w (32768)
#define O6 4293122       // new_embedding (32768)

// ws float layout:
// [0..512)          = ee (||e_k||^2)
// [512..4608)       = counts, 8 replicas x 512 (int)
// [4608..6656)      = per-block loss partials (2048)
// [6656]            = n (0.99*sum(ema_cs) + 0.01*65536)
// [6912..269056)    = dw, 8 replicas x 32768
// [269056..)        = B-pack (98304 bf16, MFMA-frag order)
#define WS_EE   0
#define WS_CNT  512
#define WS_LOSS 4608
#define WS_N    6656
#define WS_DW   6912
#define WS_BP   269056

typedef __bf16 bf16x8 __attribute__((ext_vector_type(8)));
typedef float  f32x4  __attribute__((ext_vector_type(4)));

union U2 { unsigned int u; unsigned short us[2]; __bf16 h[2]; };

__global__ void k0_init(const float* __restrict__ emb, const float* __restrict__ ema_cs,
                        float* __restrict__ wsf) {
    __shared__ float sn[256];
    const int b = blockIdx.x, t = threadIdx.x;
    if (b < 128) {
        #pragma unroll
        for (int i = 0; i < 8; ++i)                      // zero 8 dw replicas (2048 f/block)
            wsf[WS_DW + b * 2048 + i * 256 + t] = 0.0f;
    } else if (b == 128) {
        int* cnt = (int*)(wsf + WS_CNT);
        #pragma unroll
        for (int i = 0; i < 16; ++i) cnt[i * 256 + t] = 0;  // zero 8 cnt replicas
        sn[t] = ema_cs[t] + ema_cs[t + 256];
        __syncthreads();
        for (int s = 128; s > 0; s >>= 1) {
            if (t < s) sn[t] += sn[t + s];
            __syncthreads();
        }
        if (t == 0) wsf[WS_N] = 0.99f * sn[0] + 0.01f * 65536.0f;  // n (counts sum to NVEC)
    } else if (b < 131) {
        int k = (b - 129) * 256 + t;                     // 0..511
        const float* e = emb + k * DIM;
        float s = 0.0f;
        #pragma unroll
        for (int c = 0; c < DIM; ++c) s += e[c] * e[c];
        wsf[WS_EE + k] = s;                              // ||e_k||^2
    } else {
        // Pack bf16 3-way split of (-2*e) into MFMA B-fragment order:
        // frag(s, ntg, ks): lane l holds B^T[code = ntg*16 + (l&15)][c = ks*32 + (l>>4)*8 + j]
        int g = (b - 131) * 256 + t;                     // 0..98303
        int j    = g & 7;
        int lane = (g >> 3) & 63;
        int ks   = (g >> 9) & 1;
        int rest = g >> 10;                              // 0..95
        int ntg  = rest & 31;
        int s    = rest >> 5;                            // split 0..2
        int code = ntg * 16 + (lane & 15);
        int c    = ks * 32 + (lane >> 4) * 8 + j;
        float v = -2.0f * emb[code * DIM + c];
        __bf16 h0 = (__bf16)v;  float r1 = v  - (float)h0;
        __bf16 h1 = (__bf16)r1; float r2 = r1 - (float)h1;
        __bf16 hv = (s == 0) ? h0 : (s == 1 ? h1 : (__bf16)r2);
        ((__bf16*)(wsf + WS_BP))[g] = hv;
    }
}

// Block: 256 threads = 4 waves; 32 vectors x 512 codes per block (2048 blocks).
// Wave ni: 32-vector x 128-code tile = 2x8 MFMA 16x16 tiles, acc[2][8]=64 AGPR.
// K-loop: 12 flat phases (ks,s,bh), 2-deep B prefetch (counted vmcnt), all A
// fragments hoisted to registers -> pure global-load || MFMA pipeline.
__global__ __launch_bounds__(256, 4)
void k1_main(const float* __restrict__ in, const float* __restrict__ emb,
             float* __restrict__ out, float* __restrict__ wsf) {
    __shared__ unsigned int xsp[3][32 * 36]; // bf16 splits, packed pairs; row stride 36 uints
    __shared__ float xxp[32][9];             // per-thread ||x||^2 partials
    __shared__ float pmin[4][32];
    __shared__ int   pidx[4][32];
    __shared__ float xxs[32];
    __shared__ int   hist[K_CODES];

    const int t    = threadIdx.x;
    const int lane = t & 63;
    const int wave = t >> 6;           // 0..3
    const int ni   = wave;             // 128-code quarter
    const int col  = lane & 15;
    const int quad = lane >> 4;

    hist[t] = 0; hist[t + 256] = 0;

    const int blk     = blockIdx.x;                    // 0..2047
    const int rep     = blk & (NREP - 1);              // atomic replica
    const int n_img   = blk >> 5;
    const int hw_base = (blk & 31) * 32;
    const float* xbase = in + n_img * (DIM * HW) + hw_base;

    // Accumulators init with ||e||^2 (d = ee - 2<x,e>)
    f32x4 acc[2][8];
    #pragma unroll
    for (int nt = 0; nt < 8; ++nt) {
        float eev = wsf[WS_EE + ni * 128 + nt * 16 + col];
        #pragma unroll
        for (int mi = 0; mi < 2; ++mi) {
            acc[mi][nt][0] = eev; acc[mi][nt][1] = eev;
            acc[mi][nt][2] = eev; acc[mi][nt][3] = eev;
        }
    }

    // Fused stage + bf16 3-split build: thread t owns row h = t&31, column
    // pairs cp = it*8 + (t>>5). Coalesced 128B global reads per half-wave.
    {
        const int h   = t & 31;
        const int cp0 = t >> 5;
        float xxa = 0.0f;
        #pragma unroll
        for (int it = 0; it < 4; ++it) {
            int cp = it * 8 + cp0;
            float v0 = xbase[(2 * cp) * HW + h];
            float v1 = xbase[(2 * cp + 1) * HW + h];
            __bf16 a0 = (__bf16)v0; float ra = v0 - (float)a0;
            __bf16 a1 = (__bf16)ra; ra -= (float)a1;
            __bf16 a2 = (__bf16)ra;
            __bf16 b0 = (__bf16)v1; float rb = v1 - (float)b0;
            __bf16 b1 = (__bf16)rb; rb -= (float)b1;
            __bf16 b2 = (__bf16)rb;
            U2 u0, u1, u2;
            u0.h[0] = a0; u0.h[1] = b0;
            u1.h[0] = a1; u1.h[1] = b1;
            u2.h[0] = a2; u2.h[1] = b2;
            xsp[0][h * 36 + cp] = u0.u;
            xsp[1][h * 36 + cp] = u1.u;
            xsp[2][h * 36 + cp] = u2.u;
            xxa += v0 * v0 + v1 * v1;
        }
        xxp[h][cp0] = xxa;
    }

    const bf16x8* bp8 = (const bf16x8*)(wsf + WS_BP);

    // Prologue: issue B loads for phases 0 and 1 BEFORE the barrier (addresses
    // are LDS-independent; the barrier drain covers their latency).
    bf16x8 Bp[3][4];
    #pragma unroll
    for (int n4 = 0; n4 < 4; ++n4)                       // phase 0: ks=0,s=0,bh=0
        Bp[0][n4] = bp8[(((0 * 32 + ni * 8 + 0 * 4 + n4) * 2 + 0) * 64) + lane];
    #pragma unroll
    for (int n4 = 0; n4 < 4; ++n4)                       // phase 1: ks=0,s=0,bh=1
        Bp[1][n4] = bp8[(((0 * 32 + ni * 8 + 1 * 4 + n4) * 2 + 0) * 64) + lane];

    __syncthreads();

    // ||x||^2 per vector
    if (t < 32) {
        float s = 0.0f;
        #pragma unroll
        for (int j = 0; j < 8; ++j) s += xxp[t][j];
        xxs[t] = s;
    }

    // Hoist ALL A fragments (both ks) to registers: 12x ds_read_b128 = 48 VGPR
    bf16x8 Af[2][3][2];                                  // [ks][split][mi]
    #pragma unroll
    for (int ks = 0; ks < 2; ++ks)
        #pragma unroll
        for (int mi = 0; mi < 2; ++mi) {
            int u = (mi * 16 + col) * 36 + ks * 16 + quad * 4;
            Af[ks][0][mi] = *(const bf16x8*)&xsp[0][u];
            Af[ks][1][mi] = *(const bf16x8*)&xsp[1][u];
            Af[ks][2][mi] = *(const bf16x8*)&xsp[2][u];
        }

    // 12-phase pipeline: phase p = (ks = p/6, s = (p%6)/2, bh = p&1).
    // Issue loads for p+2 (into Bp[(p+2)%3]), MFMA on Bp[p%3].
    #pragma unroll
    for (int p = 0; p < 12; ++p) {
        const int ks = p / 6, s = (p % 6) / 2, bh = p & 1;
        if (p < 10) {
            const int pn = p + 2;
            const int ksn = pn / 6, sn = (pn % 6) / 2, bhn = pn & 1;
            #pragma unroll
            for (int n4 = 0; n4 < 4; ++n4)
                Bp[pn % 3][n4] = bp8[(((sn * 32 + ni * 8 + bhn * 4 + n4) * 2 + ksn) * 64) + lane];
        }
        #pragma unroll
        for (int mi = 0; mi < 2; ++mi)
            #pragma unroll
            for (int n4 = 0; n4 < 4; ++n4)
                acc[mi][bh * 4 + n4] = __builtin_amdgcn_mfma_f32_16x16x32_bf16(
                    Af[ks][0][mi], Bp[p % 3][n4], acc[mi][bh * 4 + n4], 0, 0, 0);
        if (s < 2) {
            #pragma unroll
            for (int mi = 0; mi < 2; ++mi)
                #pragma unroll
                for (int n4 = 0; n4 < 4; ++n4)
                    acc[mi][bh * 4 + n4] = __builtin_amdgcn_mfma_f32_16x16x32_bf16(
                        Af[ks][1][mi], Bp[p % 3][n4], acc[mi][bh * 4 + n4], 0, 0, 0);
        }
        if (s == 0) {
            #pragma unroll
            for (int mi = 0; mi < 2; ++mi)
                #pragma unroll
                for (int n4 = 0; n4 < 4; ++n4)
                    acc[mi][bh * 4 + n4] = __builtin_amdgcn_mfma_f32_16x16x32_bf16(
                        Af[ks][2][mi], Bp[p % 3][n4], acc[mi][bh * 4 + n4], 0, 0, 0);
        }
    }

    // Argmin. C layout: col(code) = lane&15, row(vector) = quad*4 + reg.
    #pragma unroll
    for (int mi = 0; mi < 2; ++mi) {
        #pragma unroll
        for (int r = 0; r < 4; ++r) {
            float v  = acc[mi][0][r];
            int   bi = ni * 128 + col;
            #pragma unroll
            for (int nt = 1; nt < 8; ++nt) {            // ascending codes, strict < = first-min
                float u  = acc[mi][nt][r];
                int   ui = ni * 128 + nt * 16 + col;
                if (u < v) { v = u; bi = ui; }
            }
            #pragma unroll
            for (int off = 1; off < 16; off <<= 1) {    // 16-lane butterfly, idx tie-break
                float ov = __shfl_xor(v, off);
                int   oi = __shfl_xor(bi, off);
                if (ov < v || (ov == v && oi < bi)) { v = ov; bi = oi; }
            }
            if (col == 0) {
                int row = mi * 16 + quad * 4 + r;
                pmin[ni][row] = v;
                pidx[ni][row] = bi;
            }
        }
    }
    __syncthreads();

    // Combine the 4 n-quarters (ascending code ranges), then idx/loss/hist
    if (t < 32) {
        float v = pmin[0][t]; int bi = pidx[0][t];
        #pragma unroll
        for (int q = 1; q < 4; ++q) {
            float u = pmin[q][t]; int ui = pidx[q][t];
            if (u < v) { v = u; bi = ui; }
        }
        pidx[0][t] = bi;                                 // publish final idx
        out[O3 + blk * 32 + t] = (float)bi;
        atomicAdd(&hist[bi], 1);
        float ld = v + xxs[t];                           // d_min = xx + (ee - 2<x,e>)
        #pragma unroll
        for (int off = 16; off > 0; off >>= 1) ld += __shfl_down(ld, off);
        if (t == 0) wsf[WS_LOSS + blk] = ld;             // per-block loss partial
    }
    __syncthreads();

    // out_q: thread t -> vector v = t&31, c-octant t>>5; coalesced per c-plane
    {
        int v = t & 31, cq = t >> 5;
        int kv = pidx[0][v];
        const float* ew = emb + kv * DIM;
        float* oq = out + O1 + n_img * (DIM * HW) + hw_base + v;
        #pragma unroll
        for (int c = cq * 8; c < cq * 8 + 8; ++c) oq[c * HW] = ew[c];
    }

    // dw: wave w -> rows [w*8, w*8+8); value reconstructed from the 3 splits
    // (exact to ~2^-24); fire-and-forget coalesced atomic row adds
    {
        float* dwr = wsf + WS_DW + rep * 32768;
        #pragma unroll
        for (int v8 = 0; v8 < 8; ++v8) {
            int v  = wave * 8 + v8;
            int kv = pidx[0][v];
            int wi = v * 36 + (lane >> 1);
            U2 a0, a1, a2;
            a0.u = xsp[0][wi]; a1.u = xsp[1][wi]; a2.u = xsp[2][wi];
            int hs = lane & 1;
            float val = (float)a0.h[hs] + (float)a1.h[hs] + (float)a2.h[hs];
            atomicAdd(&dwr[kv * 64 + lane], val);
        }
    }

    // counts: tiny int atomics (histogram-compacted)
    int* cnt = (int*)(wsf + WS_CNT);
    if (hist[t])       atomicAdd(&cnt[rep * 512 + t], hist[t]);
    if (hist[t + 256]) atomicAdd(&cnt[rep * 512 + t + 256], hist[t + 256]);
}

// Merged epilogue: blocks 0..127 = new_ema_w / new_embedding / new_cs (coalesced);
// block 128 = loss + perplexity.
__global__ void k2(const float* __restrict__ ema_cs, const float* __restrict__ ema_w,
                   float* __restrict__ out, const float* __restrict__ wsf) {
    __shared__ float s1[256], s2[256];
    const int t = threadIdx.x;
    const int blk = blockIdx.x;
    const int* cnt = (const int*)(wsf + WS_CNT);

    if (blk == 128) {
        // loss: sum 2048 per-block partials
        float ls = 0.0f;
        #pragma unroll
        for (int j = 0; j < 8; ++j) ls += wsf[WS_LOSS + j * 256 + t];
        s1[t] = ls;
        // perplexity from counts
        float ca = 0.0f, cb = 0.0f;
        #pragma unroll
        for (int r = 0; r < NREP; ++r) {
            ca += (float)cnt[r * 512 + t];
            cb += (float)cnt[r * 512 + 256 + t];
        }
        float pa = ca * (1.0f / 65536.0f);
        float pb = cb * (1.0f / 65536.0f);
        s2[t] = pa * logf(pa + 1e-10f) + pb * logf(pb + 1e-10f);
        __syncthreads();
        for (int s = 128; s > 0; s >>= 1) {
            if (t < s) { s1[t] += s1[t + s]; s2[t] += s2[t + s]; }
            __syncthreads();
        }
        if (t == 0) {
            out[O0] = 0.25f * s1[0] * (1.0f / 4194304.0f);
            out[O2] = expf(-s2[0]);
        }
        return;
    }

    const int m = blk * 256 + t;                         // 0..32767
    const int k = m >> 6;
    float ck = 0.0f, dwsum = 0.0f;
    #pragma unroll
    for (int r = 0; r < NREP; ++r) {
        ck    += (float)cnt[r * 512 + k];
        dwsum += wsf[WS_DW + r * 32768 + m];
    }
    float n    = wsf[WS_N];
    float rawk = 0.99f * ema_cs[k] + 0.01f * ck;
    float csk  = (rawk + 1e-5f) / (n + 512.0f * 1e-5f) * n;   // Laplace smoothing
    float wv   = 0.99f * ema_w[m] + 0.01f * dwsum;
    out[O5 + m] = wv;
    out[O6 + m] = wv / csk;
    if ((m & 63) == 0) out[O4 + k] = csk;
}

extern "C" void kernel_launch(void* const* d_in, const int* in_sizes, int n_in,
                              void* d_out, int out_size, void* d_ws, size_t ws_size,
                              hipStream_t stream) {
    const float* in     = (const float*)d_in[0];   // inputs  (64,64,32,32) NCHW
    const float* emb    = (const float*)d_in[1];   // embedding (512,64)
    const float* ema_w  = (const float*)d_in[2];   // ema_w (512,64)
    const float* ema_cs = (const float*)d_in[3];   // ema_cluster_size (512)
    float* out = (float*)d_out;
    float* wsf = (float*)d_ws;

    hipLaunchKernelGGL(k0_init, dim3(515),  dim3(256), 0, stream, emb, ema_cs, wsf);
    hipLaunchKernelGGL(k1_main, dim3(2048), dim3(256), 0, stream, in, emb, out, wsf);
    hipLaunchKernelGGL(k2,      dim3(129),  dim3(256), 0, stream, ema_cs, ema_w, out, wsf);
}